// Round 1
// baseline (561.893 us; speedup 1.0000x reference)
//
#include <hip/hip_runtime.h>

// PillarFeatureNet: h = relu(BN(x@W^T + b)); scatter-add h into (512,512,64) grid.
// BN batch stats computed analytically from x's 6x6 covariance (b cancels in var).

constexpr int NPTS = 2000000;
constexpr int NPY  = 512;
constexpr int OUTF = 64;
constexpr float EPS = 1e-5f;

// Workspace layout (floats):
constexpr int WS_S1 = 0;    // 6  column sums of x
constexpr int WS_S2 = 6;    // 21 upper-tri sums of x_k*x_l
constexpr int WS_WP = 32;   // 64*6 folded weights  W'[j*6+k]
constexpr int WS_BP = 416;  // 64   folded bias     b'[j]

__device__ __forceinline__ float wave_sum64(float v) {
#pragma unroll
    for (int off = 32; off > 0; off >>= 1) v += __shfl_down(v, off, 64);
    return v;
}

__global__ __launch_bounds__(256) void stats_kernel(const float* __restrict__ x,
                                                    float* __restrict__ ws) {
    float acc[27];
#pragma unroll
    for (int i = 0; i < 27; ++i) acc[i] = 0.f;

    const int tid    = blockIdx.x * blockDim.x + threadIdx.x;
    const int stride = gridDim.x * blockDim.x;
    for (int p = tid; p < NPTS; p += stride) {
        float v[6];
#pragma unroll
        for (int k = 0; k < 6; ++k) v[k] = x[p * 6 + k];
        int c = 6;
#pragma unroll
        for (int k = 0; k < 6; ++k) {
            acc[k] += v[k];
#pragma unroll
            for (int l = k; l < 6; ++l) { acc[c] += v[k] * v[l]; ++c; }
        }
    }

    __shared__ float part[4][27];
    const int lane = threadIdx.x & 63;
    const int wv   = threadIdx.x >> 6;
#pragma unroll
    for (int i = 0; i < 27; ++i) {
        float s = wave_sum64(acc[i]);
        if (lane == 0) part[wv][i] = s;
    }
    __syncthreads();
    if (threadIdx.x < 27) {
        float s = part[0][threadIdx.x] + part[1][threadIdx.x] +
                  part[2][threadIdx.x] + part[3][threadIdx.x];
        unsafeAtomicAdd(&ws[threadIdx.x], s);
    }
}

__global__ void finalize_kernel(const float* W, const float* b,
                                const float* gamma, const float* beta,
                                float* ws) {
    __shared__ float m[6];
    __shared__ float C[36];
    if (threadIdx.x == 0) {
        const float invN = 1.0f / (float)NPTS;
        float mm[6];
        for (int k = 0; k < 6; ++k) { mm[k] = ws[WS_S1 + k] * invN; m[k] = mm[k]; }
        int c = 0;
        for (int k = 0; k < 6; ++k)
            for (int l = k; l < 6; ++l) {
                float cov = ws[WS_S2 + c] * invN - mm[k] * mm[l];
                ++c;
                C[k * 6 + l] = cov;
                C[l * 6 + k] = cov;
            }
    }
    __syncthreads();
    const int j = threadIdx.x;  // 64 threads
    float w[6];
#pragma unroll
    for (int k = 0; k < 6; ++k) w[k] = W[j * 6 + k];
    float mh = b[j];
#pragma unroll
    for (int k = 0; k < 6; ++k) mh += w[k] * m[k];
    float var = 0.f;
#pragma unroll
    for (int k = 0; k < 6; ++k)
#pragma unroll
        for (int l = 0; l < 6; ++l) var += w[k] * w[l] * C[k * 6 + l];
    const float s = gamma[j] * rsqrtf(var + EPS);
#pragma unroll
    for (int k = 0; k < 6; ++k) ws[WS_WP + j * 6 + k] = w[k] * s;
    ws[WS_BP + j] = beta[j] + s * (b[j] - mh);
}

__global__ __launch_bounds__(256) void scatter_kernel(const float* __restrict__ x,
                                                      const int* __restrict__ idx,
                                                      const float* __restrict__ ws,
                                                      float* __restrict__ grid) {
    const int lane  = threadIdx.x & 63;
    const int wave  = blockIdx.x * (blockDim.x >> 6) + (threadIdx.x >> 6);
    const int nwave = gridDim.x * (blockDim.x >> 6);

    // lane j holds feature j's folded weights in registers
    const float w0 = ws[WS_WP + lane * 6 + 0];
    const float w1 = ws[WS_WP + lane * 6 + 1];
    const float w2 = ws[WS_WP + lane * 6 + 2];
    const float w3 = ws[WS_WP + lane * 6 + 3];
    const float w4 = ws[WS_WP + lane * 6 + 4];
    const float w5 = ws[WS_WP + lane * 6 + 5];
    const float bb = ws[WS_BP + lane];

    for (int p = wave; p < NPTS; p += nwave) {
        const float* xp = x + (size_t)p * 6;
        float xv = (lane < 6) ? xp[lane] : 0.f;   // 1 VMEM; broadcast via shuffle
        const int2 ij = ((const int2*)idx)[p];    // wave-uniform 8B load
        float acc = bb;
        acc += w0 * __shfl(xv, 0, 64);
        acc += w1 * __shfl(xv, 1, 64);
        acc += w2 * __shfl(xv, 2, 64);
        acc += w3 * __shfl(xv, 3, 64);
        acc += w4 * __shfl(xv, 4, 64);
        acc += w5 * __shfl(xv, 5, 64);
        if (acc > 0.f) {
            unsafeAtomicAdd(&grid[((size_t)ij.x * NPY + ij.y) * OUTF + lane], acc);
        }
    }
}

extern "C" void kernel_launch(void* const* d_in, const int* in_sizes, int n_in,
                              void* d_out, int out_size, void* d_ws, size_t ws_size,
                              hipStream_t stream) {
    const float* x       = (const float*)d_in[0];
    const int*   indices = (const int*)d_in[1];
    const float* W       = (const float*)d_in[2];
    const float* b       = (const float*)d_in[3];
    const float* gamma   = (const float*)d_in[4];
    const float* beta    = (const float*)d_in[5];
    float* out = (float*)d_out;
    float* ws  = (float*)d_ws;

    hipMemsetAsync(ws, 0, 27 * sizeof(float), stream);
    hipMemsetAsync(d_out, 0, (size_t)out_size * sizeof(float), stream);

    stats_kernel<<<1024, 256, 0, stream>>>(x, ws);
    finalize_kernel<<<1, 64, 0, stream>>>(W, b, gamma, beta, ws);
    scatter_kernel<<<8192, 256, 0, stream>>>(x, indices, ws, out);
}

// Round 2
// 458.875 us; speedup vs baseline: 1.2245x; 1.2245x over previous
//
#include <hip/hip_runtime.h>

// PillarFeatureNet: out = scatter_add(relu(BN(x@W^T + b)), cells), grid 512x512x64.
// BN batch stats computed analytically from x's 6x6 covariance (bias b cancels in var),
// then BN+ReLU folded into the linear: h = relu(x @ W'^T + b').
// Scatter-add done via counting sort by cell -> one wave per cell, register
// accumulation, single coalesced store per cell. No 4B atomics on the 67MB grid.

constexpr int NPTS   = 2000000;
constexpr int NPY    = 512;
constexpr int NCELLS = 512 * 512;
constexpr int OUTF   = 64;
constexpr float EPS  = 1e-5f;

// Workspace layout (4-byte elements):
constexpr int WS_S1     = 0;                    // 27 stats (6 sums + 21 upper-tri products)
constexpr int WS_WP     = 32;                   // 64*6 folded weights
constexpr int WS_BP     = 416;                  // 64 folded bias
constexpr int WS_BSUM   = 512;                  // 512 block sums for scan
constexpr int WS_HIST   = 1024;                 // 262144 per-cell counts
constexpr int WS_STARTS = WS_HIST + NCELLS;     // 262144 cell start offsets
constexpr int WS_CURSOR = WS_STARTS + NCELLS;   // 262144 cursors (== ends after bucket pass)
constexpr int WS_SORTED = WS_CURSOR + NCELLS;   // 2000000 sorted point ids
// total = 2,787,456 elements = ~10.7 MB

__device__ __forceinline__ float wave_sum64(float v) {
#pragma unroll
    for (int off = 32; off > 0; off >>= 1) v += __shfl_down(v, off, 64);
    return v;
}

// ---------------- Pass 1: x stats + cell histogram (fused) ----------------
__global__ __launch_bounds__(256) void stats_hist_kernel(const float* __restrict__ x,
                                                         const int2* __restrict__ idx,
                                                         float* __restrict__ ws,
                                                         int* __restrict__ hist) {
    float acc[27];
#pragma unroll
    for (int i = 0; i < 27; ++i) acc[i] = 0.f;

    const int tid    = blockIdx.x * blockDim.x + threadIdx.x;
    const int stride = gridDim.x * blockDim.x;
    for (int p = tid; p < NPTS; p += stride) {
        const int2 ij = idx[p];
        atomicAdd(&hist[ij.x * NPY + ij.y], 1);
        float v[6];
#pragma unroll
        for (int k = 0; k < 6; ++k) v[k] = x[(size_t)p * 6 + k];
        int c = 6;
#pragma unroll
        for (int k = 0; k < 6; ++k) {
            acc[k] += v[k];
#pragma unroll
            for (int l = k; l < 6; ++l) { acc[c] += v[k] * v[l]; ++c; }
        }
    }

    __shared__ float part[4][27];
    const int lane = threadIdx.x & 63;
    const int wv   = threadIdx.x >> 6;
#pragma unroll
    for (int i = 0; i < 27; ++i) {
        float s = wave_sum64(acc[i]);
        if (lane == 0) part[wv][i] = s;
    }
    __syncthreads();
    if (threadIdx.x < 27) {
        float s = part[0][threadIdx.x] + part[1][threadIdx.x] +
                  part[2][threadIdx.x] + part[3][threadIdx.x];
        unsafeAtomicAdd(&ws[threadIdx.x], s);
    }
}

// ---------------- Pass 2a: per-block (512-bin) totals ----------------
__global__ __launch_bounds__(256) void scan_reduce_kernel(const int* __restrict__ hist,
                                                          int* __restrict__ bsum) {
    __shared__ int lds[4];
    const int base = blockIdx.x * 512;
    const int t    = threadIdx.x;
    int v = hist[base + 2 * t] + hist[base + 2 * t + 1];
#pragma unroll
    for (int d = 32; d > 0; d >>= 1) v += __shfl_down(v, d, 64);
    if ((t & 63) == 0) lds[t >> 6] = v;
    __syncthreads();
    if (t == 0) bsum[blockIdx.x] = lds[0] + lds[1] + lds[2] + lds[3];
}

// ---------------- Pass 2b: scan 512 block totals + finalize BN fold ----------------
__global__ __launch_bounds__(512) void scan_mid_finalize_kernel(int* __restrict__ bsum,
                                                                const float* __restrict__ W,
                                                                const float* __restrict__ b,
                                                                const float* __restrict__ gamma,
                                                                const float* __restrict__ beta,
                                                                float* __restrict__ ws) {
    __shared__ int slds[8];
    const int t    = threadIdx.x;
    const int lane = t & 63;
    const int wv   = t >> 6;
    const int v    = bsum[t];
    int incl = v;
#pragma unroll
    for (int d = 1; d < 64; d <<= 1) {
        int u = __shfl_up(incl, d, 64);
        if (lane >= d) incl += u;
    }
    if (lane == 63) slds[wv] = incl;
    __syncthreads();
    int pre = 0;
#pragma unroll
    for (int w = 0; w < 8; ++w) {
        int sv = slds[w];
        if (w < wv) pre += sv;
    }
    bsum[t] = pre + incl - v;  // exclusive prefix of block totals

    // ---- BN fold (depends only on pass 1) ----
    __shared__ float m[6];
    __shared__ float C[36];
    __syncthreads();
    if (t == 0) {
        const float invN = 1.0f / (float)NPTS;
        float mm[6];
        for (int k = 0; k < 6; ++k) { mm[k] = ws[WS_S1 + k] * invN; m[k] = mm[k]; }
        int c = 6;
        for (int k = 0; k < 6; ++k)
            for (int l = k; l < 6; ++l) {
                float cov = ws[c] * invN - mm[k] * mm[l];
                ++c;
                C[k * 6 + l] = cov;
                C[l * 6 + k] = cov;
            }
    }
    __syncthreads();
    if (t < 64) {
        float w[6];
#pragma unroll
        for (int k = 0; k < 6; ++k) w[k] = W[t * 6 + k];
        float mh = b[t];
#pragma unroll
        for (int k = 0; k < 6; ++k) mh += w[k] * m[k];
        float var = 0.f;
#pragma unroll
        for (int k = 0; k < 6; ++k)
#pragma unroll
            for (int l = 0; l < 6; ++l) var += w[k] * w[l] * C[k * 6 + l];
        const float s = gamma[t] * rsqrtf(var + EPS);
#pragma unroll
        for (int k = 0; k < 6; ++k) ws[WS_WP + t * 6 + k] = w[k] * s;
        ws[WS_BP + t] = beta[t] + s * (b[t] - mh);
    }
}

// ---------------- Pass 2c: per-bin exclusive scan -> starts & cursor ----------------
__global__ __launch_bounds__(256) void scan_write_kernel(const int* __restrict__ hist,
                                                         const int* __restrict__ bsum,
                                                         int* __restrict__ starts,
                                                         int* __restrict__ cursor) {
    __shared__ int slds[4];
    const int base = blockIdx.x * 512;
    const int t    = threadIdx.x;
    const int lane = t & 63;
    const int wv   = t >> 6;
    const int v0 = hist[base + 2 * t];
    const int v1 = hist[base + 2 * t + 1];
    const int v  = v0 + v1;
    int incl = v;
#pragma unroll
    for (int d = 1; d < 64; d <<= 1) {
        int u = __shfl_up(incl, d, 64);
        if (lane >= d) incl += u;
    }
    if (lane == 63) slds[wv] = incl;
    __syncthreads();
    int pre = 0;
#pragma unroll
    for (int w = 0; w < 4; ++w) {
        int sv = slds[w];
        if (w < wv) pre += sv;
    }
    const int excl = pre + incl - v + bsum[blockIdx.x];
    starts[base + 2 * t]     = excl;
    starts[base + 2 * t + 1] = excl + v0;
    cursor[base + 2 * t]     = excl;
    cursor[base + 2 * t + 1] = excl + v0;
}

// ---------------- Pass 3: bucket point ids by cell ----------------
__global__ __launch_bounds__(256) void bucket_kernel(const int2* __restrict__ idx,
                                                     int* __restrict__ cursor,
                                                     int* __restrict__ sorted) {
    const int p = blockIdx.x * 256 + threadIdx.x;
    if (p >= NPTS) return;
    const int2 ij = idx[p];
    const int pos = atomicAdd(&cursor[ij.x * NPY + ij.y], 1);
    sorted[pos] = p;
}

// ---------------- Pass 4: one wave per cell, accumulate + store ----------------
__device__ __forceinline__ float relu_h(const float* __restrict__ x, int pid,
                                        float w0, float w1, float w2,
                                        float w3, float w4, float w5, float bb) {
    const float2* xp = (const float2*)(x + (size_t)pid * 6);
    const float2 a = xp[0];
    const float2 b = xp[1];
    const float2 c = xp[2];
    float h = bb;
    h += w0 * a.x; h += w1 * a.y;
    h += w2 * b.x; h += w3 * b.y;
    h += w4 * c.x; h += w5 * c.y;
    return fmaxf(h, 0.f);
}

__global__ __launch_bounds__(256) void accum_kernel(const float* __restrict__ x,
                                                    const int* __restrict__ sorted,
                                                    const int* __restrict__ starts,
                                                    const int* __restrict__ cursor,
                                                    const float* __restrict__ ws,
                                                    float* __restrict__ grid) {
    const int lane  = threadIdx.x & 63;
    const int cellw = blockIdx.x * 4 + (threadIdx.x >> 6);
    // Force wave-uniformity so pid/x loads become scalar (broadcast) loads:
    const int cell = __builtin_amdgcn_readfirstlane(cellw);

    const float w0 = ws[WS_WP + lane * 6 + 0];
    const float w1 = ws[WS_WP + lane * 6 + 1];
    const float w2 = ws[WS_WP + lane * 6 + 2];
    const float w3 = ws[WS_WP + lane * 6 + 3];
    const float w4 = ws[WS_WP + lane * 6 + 4];
    const float w5 = ws[WS_WP + lane * 6 + 5];
    const float bb = ws[WS_BP + lane];

    const int s = starts[cell];
    const int e = cursor[cell];  // after bucket pass, cursor[c] == start + count

    float acc = 0.f;
    int i = s;
    for (; i + 4 <= e; i += 4) {
        const int p0 = sorted[i + 0];
        const int p1 = sorted[i + 1];
        const int p2 = sorted[i + 2];
        const int p3 = sorted[i + 3];
        acc += relu_h(x, p0, w0, w1, w2, w3, w4, w5, bb);
        acc += relu_h(x, p1, w0, w1, w2, w3, w4, w5, bb);
        acc += relu_h(x, p2, w0, w1, w2, w3, w4, w5, bb);
        acc += relu_h(x, p3, w0, w1, w2, w3, w4, w5, bb);
    }
    for (; i < e; ++i) {
        acc += relu_h(x, sorted[i], w0, w1, w2, w3, w4, w5, bb);
    }
    grid[(size_t)cell * OUTF + lane] = acc;  // every cell written exactly once -> no memset
}

extern "C" void kernel_launch(void* const* d_in, const int* in_sizes, int n_in,
                              void* d_out, int out_size, void* d_ws, size_t ws_size,
                              hipStream_t stream) {
    const float* x       = (const float*)d_in[0];
    const int2*  indices = (const int2*)d_in[1];
    const float* W       = (const float*)d_in[2];
    const float* b       = (const float*)d_in[3];
    const float* gamma   = (const float*)d_in[4];
    const float* beta    = (const float*)d_in[5];
    float* out = (float*)d_out;
    float* wsf = (float*)d_ws;
    int*   wsi = (int*)d_ws;

    int* hist   = wsi + WS_HIST;
    int* bsum   = wsi + WS_BSUM;
    int* starts = wsi + WS_STARTS;
    int* cursor = wsi + WS_CURSOR;
    int* sorted = wsi + WS_SORTED;

    // zero stats + block sums + histogram (everything else is fully overwritten)
    hipMemsetAsync(d_ws, 0, (size_t)(WS_HIST + NCELLS) * sizeof(int), stream);

    stats_hist_kernel<<<2048, 256, 0, stream>>>(x, indices, wsf, hist);
    scan_reduce_kernel<<<512, 256, 0, stream>>>(hist, bsum);
    scan_mid_finalize_kernel<<<1, 512, 0, stream>>>(bsum, W, b, gamma, beta, wsf);
    scan_write_kernel<<<512, 256, 0, stream>>>(hist, bsum, starts, cursor);
    bucket_kernel<<<(NPTS + 255) / 256, 256, 0, stream>>>(indices, cursor, sorted);
    accum_kernel<<<NCELLS / 4, 256, 0, stream>>>(x, sorted, starts, cursor, wsf, out);
}